// Round 7
// baseline (203.939 us; speedup 1.0000x reference)
//
#include <hip/hip_runtime.h>
#include <math.h>

// ---------------------------------------------------------------------------
// CausalKernel.
//   mask_kernel: light-cone mask + Green term for all N points; wave-aggregated
//     compaction of ~9% active points with f = temporal*env/(r+1e-6); also
//     builds a zero-padded copy of the spatial kernel table in ws.
//   mode_kernel: one wave per (64-point group x mode-chunk); 64 chunks x 576
//     modes. k-chunk staged global->VGPR->LDS (double-buffered, issue-early /
//     write-late so HBM/L2 latency hides under compute); inner loop reads k
//     via uniform-address ds_read_b128 broadcasts (conflict-free) and runs the
//     stride-8 Chebyshev sin recurrence (2 FMA/mode), double-precision phase
//     anchor per chunk.
//   NOTE: dur_us has a ~84us floor from the harness's 2x256MiB d_ws poison
//   fills that replay inside the timed loop; our controllable part is
//   mask (~3us) + mode (~41us at round 5, target ~16us).
// ---------------------------------------------------------------------------

constexpr int NCHUNK = 64;               // mode chunks per point (2^6)
constexpr int CH     = 576;              // modes per chunk = 36*16 = 144 float4
constexpr int MPAD   = NCHUNK * CH + 64; // zero-padded k table

__global__ __launch_bounds__(256)
void mask_kernel(const float4* __restrict__ coords,
                 const float* __restrict__ massp,
                 const float* __restrict__ coupp,
                 const float* __restrict__ tk,
                 const float* __restrict__ ksp,
                 float* __restrict__ out,
                 int* __restrict__ counter,
                 int* __restrict__ list,
                 float* __restrict__ fw,
                 float* __restrict__ rw,
                 float* __restrict__ kpad,
                 int N, int M, int MT)
{
    int i = blockIdx.x * blockDim.x + threadIdx.x;

    if (i < MPAD) kpad[i] = (i < M) ? ksp[i] : 0.0f;   // padded k table
    if (i >= N) return;

    float4 c = coords[i];
    float t = c.x;
    float rsq = c.y * c.y + c.z * c.z + c.w * c.w;
    float t2  = t * t;
    bool  fl  = (t2 >= rsq) && (t >= 0.0f);            // future light cone
    float r   = sqrtf(rsq + 1e-12f);
    float g   = 0.0f;
    if (fl && (t2 > rsq) && (t > 0.0f))                // retarded Green fn
        g = (*coupp) * __expf(-(*massp) * r) / r;
    out[i] = fl ? g : 0.0f;

    unsigned long long bal = __ballot(fl);
    if (fl) {
        float tb = 0.1f * t;
        float T  = 0.0f;
        for (int m = 1; m <= MT; ++m)
            T = fmaf(tk[m - 1], __cosf(tb * (float)m), T);
        T *= __expf(-0.1f * fabsf(t));
        float f = T / (r + 1e-6f);

        int lane   = threadIdx.x & 63;
        int prefix = __popcll(bal & ((1ull << lane) - 1ull));
        int base   = 0;
        if (prefix == 0)
            base = atomicAdd(counter, __popcll(bal));   // one atomic per wave
        int first = __ffsll(bal) - 1;
        base = __shfl(base, first);
        int pos = base + prefix;
        list[pos] = i;
        fw[pos]   = f;
        rw[pos]   = r;
    }
}

__global__ __launch_bounds__(256)
void mode_kernel(const float* __restrict__ kpad,
                 float* __restrict__ out,
                 const int* __restrict__ counter,
                 const int* __restrict__ list,
                 const float* __restrict__ fw,
                 const float* __restrict__ rw)
{
    // per-wave double-buffered k chunk: 4 waves x 2 bufs x 576 floats = 18.4 KB
    __shared__ float smem[4][2][CH];

    int gtid   = blockIdx.x * blockDim.x + threadIdx.x;
    int wave   = gtid >> 6;
    int lane   = threadIdx.x & 63;
    int wb     = (threadIdx.x >> 6) & 3;
    int nwaves = (gridDim.x * blockDim.x) >> 6;

    int count   = __builtin_amdgcn_readfirstlane(*counter);
    int ngroups = (count + 63) >> 6;
    int items   = ngroups * NCHUNK;

    int it = wave;
    if (it >= items) return;

    // ---- prologue: meta + k for first item, write LDS buf 0
    int chunk = it & (NCHUNK - 1);
    int li    = (it >> 6) * 64 + lane;          // >>6 == /NCHUNK
    int   idx = 0; float r = 0.0f, f = 0.0f;
    if (li < count) { idx = list[li]; r = rw[li]; f = fw[li]; }
    {
        const float4* kc = (const float4*)(kpad + chunk * CH);
        float4 g0 = kc[lane];
        float4 g1 = kc[lane + 64];
        float4 g2 = make_float4(0.f, 0.f, 0.f, 0.f);
        if (lane < 16) g2 = kc[lane + 128];
        float4* dst = (float4*)&smem[wb][0][0];
        dst[lane] = g0; dst[lane + 64] = g1;
        if (lane < 16) dst[lane + 128] = g2;
    }
    int cur = 0;

    while (true) {
        int  itn  = it + nwaves;
        bool last = (itn >= items);
        int  itp  = last ? it : itn;

        // ---- issue next item's loads early (latency hides under compute)
        int chunkn = itp & (NCHUNK - 1);
        int lin    = (itp >> 6) * 64 + lane;
        int   idxn = 0; float rn = 0.0f, fn = 0.0f;
        if (lin < count) { idxn = list[lin]; rn = rw[lin]; fn = fw[lin]; }
        const float4* kcn = (const float4*)(kpad + chunkn * CH);
        float4 h0 = kcn[lane];
        float4 h1 = kcn[lane + 64];
        float4 h2 = make_float4(0.f, 0.f, 0.f, 0.f);
        if (lane < 16) h2 = kcn[lane + 128];

        // ---- setup current item: dp phase anchor + seed sines
        int n0 = chunk * CH;
        double y = (double)n0 * (double)r;
        double q = rint(y * 0.15915494309189535);
        float  base = (float)(y - q * 6.283185307179586);
        float  t2c  = 2.0f * __cosf(8.0f * r);      // stride-8 Chebyshev coeff

        float sc[8], sp[8], acc[8];
#pragma unroll
        for (int j = 0; j < 8; ++j) {
            sc[j]  = __sinf(fmaf((float)j,       r, base));   // sin((n0+j) r)
            sp[j]  = __sinf(fmaf((float)(j - 8), r, base));   // sin((n0+j-8) r)
            acc[j] = 0.0f;
        }

        // ---- compute: 18 macro-steps x 32 modes from LDS (uniform broadcast)
        const float4* lk = (const float4*)&smem[wb][cur][0];
        for (int s2 = 0; s2 < 18; ++s2) {
            float4 q0 = lk[8 * s2 + 0], q1 = lk[8 * s2 + 1];
            float4 q2 = lk[8 * s2 + 2], q3 = lk[8 * s2 + 3];
            float4 q4 = lk[8 * s2 + 4], q5 = lk[8 * s2 + 5];
            float4 q6 = lk[8 * s2 + 6], q7 = lk[8 * s2 + 7];
            float kv0[8] = {q0.x, q0.y, q0.z, q0.w, q1.x, q1.y, q1.z, q1.w};
            float kv1[8] = {q2.x, q2.y, q2.z, q2.w, q3.x, q3.y, q3.z, q3.w};
            float kv2[8] = {q4.x, q4.y, q4.z, q4.w, q5.x, q5.y, q5.z, q5.w};
            float kv3[8] = {q6.x, q6.y, q6.z, q6.w, q7.x, q7.y, q7.z, q7.w};
#pragma unroll
            for (int j = 0; j < 8; ++j) {
                acc[j] = fmaf(kv0[j], sc[j], acc[j]);
                sp[j]  = fmaf(t2c, sc[j], -sp[j]);    // sp <- sin((n+8) r)
            }
#pragma unroll
            for (int j = 0; j < 8; ++j) {
                acc[j] = fmaf(kv1[j], sp[j], acc[j]);
                sc[j]  = fmaf(t2c, sp[j], -sc[j]);    // sc <- sin((n+16) r)
            }
#pragma unroll
            for (int j = 0; j < 8; ++j) {
                acc[j] = fmaf(kv2[j], sc[j], acc[j]);
                sp[j]  = fmaf(t2c, sc[j], -sp[j]);    // sp <- sin((n+24) r)
            }
#pragma unroll
            for (int j = 0; j < 8; ++j) {
                acc[j] = fmaf(kv3[j], sp[j], acc[j]);
                sc[j]  = fmaf(t2c, sp[j], -sc[j]);    // sc <- sin((n+32) r)
            }
        }

        // ---- write next item's chunk into the other buffer (data arrived)
        {
            float4* dst = (float4*)&smem[wb][cur ^ 1][0];
            dst[lane] = h0; dst[lane + 64] = h1;
            if (lane < 16) dst[lane + 128] = h2;
        }

        float S = ((acc[0] + acc[1]) + (acc[2] + acc[3])) +
                  ((acc[4] + acc[5]) + (acc[6] + acc[7]));
        if (li < count)
            atomicAdd(&out[idx], S * f);

        if (last) break;
        it = itn; chunk = chunkn; li = lin;
        idx = idxn; r = rn; f = fn; cur ^= 1;
    }
}

// Emergency fallback (ws too small / unexpected M): correct but slow.
__global__ __launch_bounds__(256)
void fallback_kernel(const float4* __restrict__ coords,
                     const float* __restrict__ ksp,
                     const float* __restrict__ tk,
                     const float* __restrict__ massp,
                     const float* __restrict__ coupp,
                     float* __restrict__ out, int N, int M, int MT)
{
    int i = blockIdx.x * blockDim.x + threadIdx.x;
    if (i >= N) return;
    float4 c = coords[i];
    float t = c.x;
    float rsq = c.y * c.y + c.z * c.z + c.w * c.w;
    float t2 = t * t;
    bool fl = (t2 >= rsq) && (t >= 0.0f);
    if (!fl) { out[i] = 0.0f; return; }
    float r = sqrtf(rsq + 1e-12f);
    float g = 0.0f;
    if ((t2 > rsq) && (t > 0.0f)) g = (*coupp) * __expf(-(*massp) * r) / r;
    float T = 0.0f, tb = 0.1f * t;
    for (int m = 1; m <= MT; ++m) T = fmaf(tk[m - 1], __cosf(tb * (float)m), T);
    T *= __expf(-0.1f * fabsf(t));
    float f = T / (r + 1e-6f);
    float S = 0.0f;
    for (int n0 = 0; n0 < M; n0 += 1024) {
        int nh = min(n0 + 1024, M);
        double y = (double)n0 * (double)r;
        double q = rint(y * 0.15915494309189535);
        float base = (float)(y - q * 6.283185307179586);
        float s0 = __sinf(base - r), s1 = __sinf(base);
        float tc = 2.0f * __cosf(r);
        for (int n = n0; n < nh; ++n) {
            S = fmaf(ksp[n], s1, S);
            float nx = fmaf(tc, s1, -s0);
            s0 = s1; s1 = nx;
        }
    }
    out[i] = g + S * f;
}

extern "C" void kernel_launch(void* const* d_in, const int* in_sizes, int n_in,
                              void* d_out, int out_size, void* d_ws, size_t ws_size,
                              hipStream_t stream)
{
    const float4* coords = (const float4*)d_in[0];
    const float*  ksp    = (const float*)d_in[1];
    const float*  tk     = (const float*)d_in[2];
    const float*  massp  = (const float*)d_in[3];
    const float*  coupp  = (const float*)d_in[4];
    float*        out    = (float*)d_out;

    int N  = in_sizes[0] / 4;
    int M  = in_sizes[1];
    int MT = in_sizes[2];

    size_t off_list = 16;
    size_t off_fw   = off_list + (size_t)N * 4;
    size_t off_rw   = off_fw   + (size_t)N * 4;
    size_t off_k    = off_rw   + (size_t)N * 4;
    size_t needed   = off_k    + (size_t)MPAD * 4;

    if (ws_size < needed || M > NCHUNK * CH) {
        fallback_kernel<<<(N + 255) / 256, 256, 0, stream>>>(
            coords, ksp, tk, massp, coupp, out, N, M, MT);
        return;
    }

    int*   counter = (int*)d_ws;
    int*   list    = (int*)((char*)d_ws + off_list);
    float* fw      = (float*)((char*)d_ws + off_fw);
    float* rw      = (float*)((char*)d_ws + off_rw);
    float* kpad    = (float*)((char*)d_ws + off_k);

    hipMemsetAsync(d_ws, 0, 16, stream);

    int nthreads = (N > MPAD) ? N : MPAD;
    mask_kernel<<<(nthreads + 255) / 256, 256, 0, stream>>>(
        coords, massp, coupp, tk, ksp, out, counter, list, fw, rw, kpad, N, M, MT);

    mode_kernel<<<2048, 256, 0, stream>>>(kpad, out, counter, list, fw, rw);
}

// Round 8
// 124.987 us; speedup vs baseline: 1.6317x; 1.6317x over previous
//
#include <hip/hip_runtime.h>
#include <math.h>

// ---------------------------------------------------------------------------
// CausalKernel.
//   mask_kernel: light-cone mask + Green term for all N points; wave-aggregated
//     compaction of ~9% active points with f = temporal*env/(r+1e-6); also
//     builds a zero-padded copy of the spatial kernel table in ws.
//   mode_kernel: item = (chunk, group-pair). CHUNK-MAJOR order so co-resident
//     waves stream the SAME 2.3KB k-chunk (scalar-L1/L2 hits; round-5's
//     group-major order missed L2 18x -> FETCH 731MB). Each item processes
//     TWO 64-point groups per k-fetch: 64B k per 128cy of FMA -> latency
//     covered even on L2-hit misses. Stride-8 Chebyshev sin recurrence
//     (2 FMA/mode/point), dp phase anchor per chunk.
//   NOTE: dur_us carries a ~84us floor from the harness's 2x256MiB d_ws
//   poison fills inside the timed loop (measured round 5: 2x41.7us
//   fillBufferAligned at 80% HBM peak). Controllable part: mask + mode.
// ---------------------------------------------------------------------------

constexpr int NCHUNK = 64;               // mode chunks (2^6)
constexpr int CH     = 576;              // modes per chunk = 36*16
constexpr int MPAD   = NCHUNK * CH + 64; // zero-padded k table + overrun pad

__global__ __launch_bounds__(256)
void mask_kernel(const float4* __restrict__ coords,
                 const float* __restrict__ massp,
                 const float* __restrict__ coupp,
                 const float* __restrict__ tk,
                 const float* __restrict__ ksp,
                 float* __restrict__ out,
                 int* __restrict__ counter,
                 int* __restrict__ list,
                 float* __restrict__ fw,
                 float* __restrict__ rw,
                 float* __restrict__ kpad,
                 int N, int M, int MT)
{
    int i = blockIdx.x * blockDim.x + threadIdx.x;

    if (i < MPAD) kpad[i] = (i < M) ? ksp[i] : 0.0f;   // padded k table
    if (i >= N) return;

    float4 c = coords[i];
    float t = c.x;
    float rsq = c.y * c.y + c.z * c.z + c.w * c.w;
    float t2  = t * t;
    bool  fl  = (t2 >= rsq) && (t >= 0.0f);            // future light cone
    float r   = sqrtf(rsq + 1e-12f);
    float g   = 0.0f;
    if (fl && (t2 > rsq) && (t > 0.0f))                // retarded Green fn
        g = (*coupp) * __expf(-(*massp) * r) / r;
    out[i] = fl ? g : 0.0f;

    unsigned long long bal = __ballot(fl);
    if (fl) {
        float tb = 0.1f * t;
        float T  = 0.0f;
        for (int m = 1; m <= MT; ++m)
            T = fmaf(tk[m - 1], __cosf(tb * (float)m), T);
        T *= __expf(-0.1f * fabsf(t));
        float f = T / (r + 1e-6f);

        int lane   = threadIdx.x & 63;
        int prefix = __popcll(bal & ((1ull << lane) - 1ull));
        int base   = 0;
        if (prefix == 0)
            base = atomicAdd(counter, __popcll(bal));   // one atomic per wave
        int first = __ffsll(bal) - 1;
        base = __shfl(base, first);
        int pos = base + prefix;
        list[pos] = i;
        fw[pos]   = f;
        rw[pos]   = r;
    }
}

__global__ __launch_bounds__(256)
void mode_kernel(const float* __restrict__ kpad,
                 float* __restrict__ out,
                 const int* __restrict__ counter,
                 const int* __restrict__ list,
                 const float* __restrict__ fw,
                 const float* __restrict__ rw)
{
    int gtid   = blockIdx.x * blockDim.x + threadIdx.x;
    int wave   = gtid >> 6;
    int lane   = threadIdx.x & 63;
    int nwaves = (gridDim.x * blockDim.x) >> 6;

    int count   = __builtin_amdgcn_readfirstlane(*counter);
    int ngroups = (count + 63) >> 6;
    int ngpairs = (ngroups + 1) >> 1;       // 2 groups per item
    int items   = NCHUNK * ngpairs;

    for (int it = wave; it < items; it += nwaves) {
        // chunk-major: consecutive waves share a chunk (cache locality)
        int chunk = __builtin_amdgcn_readfirstlane(it / ngpairs);
        int gpair = it - chunk * ngpairs;

        int li0 = (gpair * 2 + 0) * 64 + lane;
        int li1 = (gpair * 2 + 1) * 64 + lane;

        bool a0 = (li0 < count), a1 = (li1 < count);
        int   idx0 = 0, idx1 = 0;
        float r0 = 0.0f, f0 = 0.0f, r1 = 0.0f, f1 = 0.0f;
        if (a0) { idx0 = list[li0]; r0 = rw[li0]; f0 = fw[li0]; }
        if (a1) { idx1 = list[li1]; r1 = rw[li1]; f1 = fw[li1]; }

        int n0 = chunk * CH;

        // dp phase anchors: base = n0*r mod 2pi
        double y0 = (double)n0 * (double)r0;
        double q0d = rint(y0 * 0.15915494309189535);
        float  b0 = (float)(y0 - q0d * 6.283185307179586);
        double y1 = (double)n0 * (double)r1;
        double q1d = rint(y1 * 0.15915494309189535);
        float  b1 = (float)(y1 - q1d * 6.283185307179586);

        float t2c0 = 2.0f * __cosf(8.0f * r0);   // stride-8 Chebyshev coeffs
        float t2c1 = 2.0f * __cosf(8.0f * r1);

        float sc0[8], sp0[8], acc0[8], sc1[8], sp1[8], acc1[8];
#pragma unroll
        for (int j = 0; j < 8; ++j) {
            sc0[j] = __sinf(fmaf((float)j,       r0, b0));
            sp0[j] = __sinf(fmaf((float)(j - 8), r0, b0));
            sc1[j] = __sinf(fmaf((float)j,       r1, b1));
            sp1[j] = __sinf(fmaf((float)(j - 8), r1, b1));
            acc0[j] = 0.0f;
            acc1[j] = 0.0f;
        }

        const float* kc = kpad + n0;             // wave-uniform -> s_load path
        float4 cA = *(const float4*)(kc);
        float4 cB = *(const float4*)(kc + 4);
        float4 cC = *(const float4*)(kc + 8);
        float4 cD = *(const float4*)(kc + 12);

        constexpr int DSTEPS = CH / 16;          // 36 guard-free double-steps
        for (int s = 0; s < DSTEPS; ++s) {
            const float* kn = kc + 16 * (s + 1); // depth-1 prefetch (pad ok)
            float4 nA = *(const float4*)(kn);
            float4 nB = *(const float4*)(kn + 4);
            float4 nC = *(const float4*)(kn + 8);
            float4 nD = *(const float4*)(kn + 12);

            float kv0[8] = {cA.x, cA.y, cA.z, cA.w, cB.x, cB.y, cB.z, cB.w};
            float kv1[8] = {cC.x, cC.y, cC.z, cC.w, cD.x, cD.y, cD.z, cD.w};
#pragma unroll
            for (int j = 0; j < 8; ++j) {
                acc0[j] = fmaf(kv0[j], sc0[j], acc0[j]);
                sp0[j]  = fmaf(t2c0, sc0[j], -sp0[j]);   // sin((n+8) r0)
                acc1[j] = fmaf(kv0[j], sc1[j], acc1[j]);
                sp1[j]  = fmaf(t2c1, sc1[j], -sp1[j]);   // sin((n+8) r1)
            }
#pragma unroll
            for (int j = 0; j < 8; ++j) {
                acc0[j] = fmaf(kv1[j], sp0[j], acc0[j]);
                sc0[j]  = fmaf(t2c0, sp0[j], -sc0[j]);   // sin((n+16) r0)
                acc1[j] = fmaf(kv1[j], sp1[j], acc1[j]);
                sc1[j]  = fmaf(t2c1, sp1[j], -sc1[j]);   // sin((n+16) r1)
            }
            cA = nA; cB = nB; cC = nC; cD = nD;
        }

        float S0 = ((acc0[0] + acc0[1]) + (acc0[2] + acc0[3])) +
                   ((acc0[4] + acc0[5]) + (acc0[6] + acc0[7]));
        float S1 = ((acc1[0] + acc1[1]) + (acc1[2] + acc1[3])) +
                   ((acc1[4] + acc1[5]) + (acc1[6] + acc1[7]));
        if (a0) atomicAdd(&out[idx0], S0 * f0);
        if (a1) atomicAdd(&out[idx1], S1 * f1);
    }
}

// Emergency fallback (ws too small / unexpected M): correct but slow.
__global__ __launch_bounds__(256)
void fallback_kernel(const float4* __restrict__ coords,
                     const float* __restrict__ ksp,
                     const float* __restrict__ tk,
                     const float* __restrict__ massp,
                     const float* __restrict__ coupp,
                     float* __restrict__ out, int N, int M, int MT)
{
    int i = blockIdx.x * blockDim.x + threadIdx.x;
    if (i >= N) return;
    float4 c = coords[i];
    float t = c.x;
    float rsq = c.y * c.y + c.z * c.z + c.w * c.w;
    float t2 = t * t;
    bool fl = (t2 >= rsq) && (t >= 0.0f);
    if (!fl) { out[i] = 0.0f; return; }
    float r = sqrtf(rsq + 1e-12f);
    float g = 0.0f;
    if ((t2 > rsq) && (t > 0.0f)) g = (*coupp) * __expf(-(*massp) * r) / r;
    float T = 0.0f, tb = 0.1f * t;
    for (int m = 1; m <= MT; ++m) T = fmaf(tk[m - 1], __cosf(tb * (float)m), T);
    T *= __expf(-0.1f * fabsf(t));
    float f = T / (r + 1e-6f);
    float S = 0.0f;
    for (int n0 = 0; n0 < M; n0 += 1024) {
        int nh = min(n0 + 1024, M);
        double y = (double)n0 * (double)r;
        double q = rint(y * 0.15915494309189535);
        float base = (float)(y - q * 6.283185307179586);
        float s0 = __sinf(base - r), s1 = __sinf(base);
        float tc = 2.0f * __cosf(r);
        for (int n = n0; n < nh; ++n) {
            S = fmaf(ksp[n], s1, S);
            float nx = fmaf(tc, s1, -s0);
            s0 = s1; s1 = nx;
        }
    }
    out[i] = g + S * f;
}

extern "C" void kernel_launch(void* const* d_in, const int* in_sizes, int n_in,
                              void* d_out, int out_size, void* d_ws, size_t ws_size,
                              hipStream_t stream)
{
    const float4* coords = (const float4*)d_in[0];
    const float*  ksp    = (const float*)d_in[1];
    const float*  tk     = (const float*)d_in[2];
    const float*  massp  = (const float*)d_in[3];
    const float*  coupp  = (const float*)d_in[4];
    float*        out    = (float*)d_out;

    int N  = in_sizes[0] / 4;
    int M  = in_sizes[1];
    int MT = in_sizes[2];

    size_t off_list = 16;
    size_t off_fw   = off_list + (size_t)N * 4;
    size_t off_rw   = off_fw   + (size_t)N * 4;
    size_t off_k    = off_rw   + (size_t)N * 4;
    size_t needed   = off_k    + (size_t)MPAD * 4;

    if (ws_size < needed || M > NCHUNK * CH) {
        fallback_kernel<<<(N + 255) / 256, 256, 0, stream>>>(
            coords, ksp, tk, massp, coupp, out, N, M, MT);
        return;
    }

    int*   counter = (int*)d_ws;
    int*   list    = (int*)((char*)d_ws + off_list);
    float* fw      = (float*)((char*)d_ws + off_fw);
    float* rw      = (float*)((char*)d_ws + off_rw);
    float* kpad    = (float*)((char*)d_ws + off_k);

    hipMemsetAsync(d_ws, 0, 16, stream);

    int nthreads = (N > MPAD) ? N : MPAD;
    mask_kernel<<<(nthreads + 255) / 256, 256, 0, stream>>>(
        coords, massp, coupp, tk, ksp, out, counter, list, fw, rw, kpad, N, M, MT);

    mode_kernel<<<2048, 256, 0, stream>>>(kpad, out, counter, list, fw, rw);
}